// Round 11
// baseline (352.680 us; speedup 1.0000x reference)
//
#include <hip/hip_runtime.h>
#include <hip/hip_bf16.h>
#include <math.h>

// CBiAFormerBlock fused implementation, round 11.
// Changes vs r10 (PASS, 316us; attn 112, rest ~204 dispatch-count-bound):
//  - 13 launches -> 9. Non-attn family flat at ~200us across r7-r10 while its
//    roofline is ~40us => serialized launch overhead dominates.
//  - setup_kernel = ln1 UNION prep (independent block ranges, one launch).
//    prep writes woff4i with row/col rows INTERLEAVED (n = 2r+coord).
//  - dwfused_kernel: all 3 depthwise convs in one launch. 64 blocks of
//    (bg, 8ch): 32x32 -> 16x16 -> 8x8 chain entirely in LDS (40KB),
//    BN+GELU fused; dw1/dw2 never touch HBM.
//  - offgrid mgemm absorbs packc (OUTM=5): interleaved weights put row/col
//    coords in adjacent lanes -> one shfl_xor pairs them; even lanes write
//    goff/gwt directly.
// attn/proj/ln2/mlp1/mlp2 byte-identical to r10.

typedef __hip_bfloat16 bf16;
typedef __bf16 bf16x8 __attribute__((ext_vector_type(8)));
typedef float f32x4 __attribute__((ext_vector_type(4)));

union U16x8 { uint4 u4; unsigned short us[8]; };

__device__ __forceinline__ float cvt(float x) { return x; }
__device__ __forceinline__ float cvt(bf16 x) { return __bfloat162float(x); }
__device__ __forceinline__ float b2f(unsigned short u) {
  union { float f; unsigned int v; } x; x.v = ((unsigned int)u) << 16; return x.f;
}
__device__ __forceinline__ unsigned short f2b(float f) {
  bf16 h = __float2bfloat16(f);
  return *reinterpret_cast<unsigned short*>(&h);
}
__device__ __forceinline__ float gelu_f(float x) {
  return 0.5f * x * (1.0f + erff(x * 0.7071067811865475f));
}

// ---------------- setup: LN1 (blocks 0..255) UNION weight prep (256..4868) --
__global__ __launch_bounds__(256) void setup_kernel(
    const float* __restrict__ x, const float* __restrict__ g,
    const float* __restrict__ bta,
    const float* __restrict__ q_w, const float* __restrict__ q_b,
    const float* __restrict__ k_w, const float* __restrict__ v_w,
    const float* __restrict__ pjw, const float* __restrict__ w1,
    const float* __restrict__ w2, const float* __restrict__ off4w,
    bf16* __restrict__ out, float* __restrict__ xnhwc,
    unsigned short* __restrict__ wqkv, float* __restrict__ bqkv,
    unsigned short* __restrict__ wproj, unsigned short* __restrict__ wmlp1,
    unsigned short* __restrict__ wmlp2, unsigned short* __restrict__ woff4i)
{
  __shared__ float s1[8][32], s2[8][32];
  __shared__ unsigned short tb[32][264];
  int bid = blockIdx.x;
  int t = threadIdx.x;
  if (bid < 256) {
    // ---- LN1: NCHW f32 -> NHWC bf16 + raw x NHWC f32 ----
    int pos = t & 31, cs = t >> 5;
    int p = bid * 32 + pos;
    int bb = p >> 12, hw = p & 4095;
    const float* xp = x + (size_t)bb * 256 * 4096 + hw;
    float vloc[32];
    float sum = 0.f, ss = 0.f;
#pragma unroll
    for (int i = 0; i < 32; ++i) {
      float v = xp[(size_t)(cs * 32 + i) * 4096];
      vloc[i] = v; sum += v; ss += v * v;
    }
    s1[cs][pos] = sum; s2[cs][pos] = ss;
    {
      float* xo = xnhwc + (size_t)p * 256 + cs * 32;
#pragma unroll
      for (int qd = 0; qd < 8; ++qd)
        *(float4*)(xo + qd * 4) = make_float4(vloc[qd*4], vloc[qd*4+1],
                                              vloc[qd*4+2], vloc[qd*4+3]);
    }
    __syncthreads();
    if (cs == 0) {
      float S = 0.f, Q = 0.f;
#pragma unroll
      for (int i = 0; i < 8; ++i) { S += s1[i][pos]; Q += s2[i][pos]; }
      float mu = S * (1.f / 256.f);
      float var = Q * (1.f / 256.f) - mu * mu;
      s1[0][pos] = mu;
      s2[0][pos] = rsqrtf(var + 1e-5f);
    }
    __syncthreads();
    float mu = s1[0][pos], rs = s2[0][pos];
#pragma unroll
    for (int i = 0; i < 32; ++i) {
      int c = cs * 32 + i;
      tb[pos][c] = f2b((vloc[i] - mu) * rs * g[c] + bta[c]);
    }
    __syncthreads();
    int px = t >> 3, grp = t & 7;
    bf16* op = out + ((size_t)bid * 32 + px) * 256 + grp * 32;
#pragma unroll
    for (int q = 0; q < 4; ++q)
      *(uint4*)(op + q * 8) = *(const uint4*)&tb[px][grp * 32 + q * 8];
  } else {
    // ---- weight prep ----
    int idx = (bid - 256) * 256 + t;
    const int S0 = 1280 * 256;
    const int S1 = S0 + 1280;
    const int S2 = S1 + 256 * 256;
    const int S3 = S2 + 1024 * 256;
    const int S4 = S3 + 256 * 1024;
    const int S5 = S4 + 2048 * 128;
    if (idx < S0) {
      int n = idx >> 8, c = idx & 255;
      float v;
      if (n < 256)       v = q_w[n * 256 + c];
      else if (n < 512)  v = (c < 128)  ? k_w[(n - 256) * 256 + c] : 0.f;
      else if (n < 768)  v = (c >= 128) ? k_w[(n - 512) * 256 + c] : 0.f;
      else if (n < 1024) v = (c < 128)  ? v_w[(n - 768) * 256 + c] : 0.f;
      else               v = (c >= 128) ? v_w[(n - 1024) * 256 + c] : 0.f;
      wqkv[idx] = f2b(v);
    } else if (idx < S1) {
      int n = idx - S0;
      bqkv[n] = (n < 256) ? q_b[n] : 0.f;
    } else if (idx < S2) {
      wproj[idx - S1] = f2b(pjw[idx - S1]);
    } else if (idx < S3) {
      wmlp1[idx - S2] = f2b(w1[idx - S2]);
    } else if (idx < S4) {
      wmlp2[idx - S3] = f2b(w2[idx - S3]);
    } else if (idx < S5) {
      int kk = idx - S4;
      int n = kk >> 7, c = kk & 127;
      // interleaved: n = 2r + coord  <-  off4w row coord*1024 + r
      woff4i[kk] = f2b(off4w[((size_t)((n & 1) * 1024 + (n >> 1))) * 128 + c]);
    }
  }
}

// ---------------- LN2: NHWC bf16 in -> NHWC bf16 out -----------------------
__global__ __launch_bounds__(256) void ln2_kernel(
    const bf16* __restrict__ xin, const float* __restrict__ g,
    const float* __restrict__ bta, bf16* __restrict__ out)
{
  __shared__ float sa[8][32], sb[8][32];
  __shared__ float mu_s[32], rs_s[32];
  int t = threadIdx.x;
  int px = t >> 3, grp = t & 7;
  size_t p = (size_t)blockIdx.x * 32 + px;
  const bf16* xp = xin + p * 256 + grp * 32;
  float v[32]; float sum = 0.f, ss = 0.f;
#pragma unroll
  for (int q = 0; q < 4; ++q) {
    U16x8 u; u.u4 = *(const uint4*)(xp + q * 8);
#pragma unroll
    for (int j = 0; j < 8; ++j) {
      float f = b2f(u.us[j]); v[q * 8 + j] = f; sum += f; ss += f * f;
    }
  }
  sa[grp][px] = sum; sb[grp][px] = ss;
  __syncthreads();
  if (t < 32) {
    float S = 0.f, Q = 0.f;
#pragma unroll
    for (int i = 0; i < 8; ++i) { S += sa[i][t]; Q += sb[i][t]; }
    float mu = S * (1.f / 256.f);
    mu_s[t] = mu;
    rs_s[t] = rsqrtf(Q * (1.f / 256.f) - mu * mu + 1e-5f);
  }
  __syncthreads();
  float mu = mu_s[px], rs = rs_s[px];
  bf16* op = out + p * 256 + grp * 32;
#pragma unroll
  for (int q = 0; q < 4; ++q) {
    U16x8 o;
#pragma unroll
    for (int j = 0; j < 8; ++j) {
      int c = grp * 32 + q * 8 + j;
      o.us[j] = f2b((v[q * 8 + j] - mu) * rs * g[c] + bta[c]);
    }
    *(uint4*)(op + q * 8) = o.u4;
  }
}

// ---------------- MFMA GEMM (NHWC): out[p][o] = sum_c A[p][c] W[o][c] ------
// OUTM: 0 bf16 NHWC; 1 f32 NCHW via LDS transpose; 4 grouped-QKV;
//       5 offset-grid head + coord pack (out=goff int32, res=gwt float4).
// RESM: 0 none; 1 f32 NHWC; 2 bf16 NHWC. ACT: 1 exact GELU.
template<int OUTM, int RESM, int ACT, int BM>
__global__ __launch_bounds__(256) void mgemm_kernel(
    const bf16* __restrict__ A, const unsigned short* __restrict__ Bw,
    const float* __restrict__ bias, const void* __restrict__ res,
    void* __restrict__ out, int N, int K, int lda, int ldb)
{
  constexpr int MT = BM / 32;
  constexpr int AB_BYTES = (BM + 64) * 72 * 2;
  constexpr int T_LD = BM + 5;
  constexpr int T_BYTES = 64 * T_LD * 4;
  constexpr int SH_BYTES = (OUTM == 1 && T_BYTES > AB_BYTES) ? T_BYTES : AB_BYTES;
  __shared__ __attribute__((aligned(16))) char shraw[SH_BYTES];
  auto As = reinterpret_cast<unsigned short(*)[72]>(shraw);
  auto Bs = reinterpret_cast<unsigned short(*)[72]>(shraw + BM * 72 * 2);
  float (*T)[T_LD] = reinterpret_cast<float(*)[T_LD]>(shraw);

  int t = threadIdx.x;
  int m0 = blockIdx.y * BM, n0 = blockIdx.x * 64;
  int lane = t & 63, w = t >> 6;
  int l15 = lane & 15, quad = lane >> 4;
  int wm = (w >> 1) * (BM / 2), wn = (w & 1) * 32;
  f32x4 acc[MT][2];
#pragma unroll
  for (int mt = 0; mt < MT; ++mt)
#pragma unroll
    for (int nt = 0; nt < 2; ++nt) acc[mt][nt] = (f32x4){0.f, 0.f, 0.f, 0.f};

  for (int k0 = 0; k0 < K; k0 += 64) {
#pragma unroll
    for (int i = 0; i < MT; ++i) {
      int idx = t + i * 256;
      int m = idx >> 3, oc = (idx & 7) * 8;
      *(uint4*)&As[m][oc] = *(const uint4*)(A + (size_t)(m0 + m) * lda + k0 + oc);
    }
#pragma unroll
    for (int i = 0; i < 2; ++i) {
      int idx = t + i * 256;
      int n = idx >> 3, oc = (idx & 7) * 8;
      *(uint4*)&Bs[n][oc] = *(const uint4*)(Bw + (size_t)(n0 + n) * ldb + k0 + oc);
    }
    __syncthreads();
#pragma unroll
    for (int ks = 0; ks < 2; ++ks) {
      bf16x8 af[MT], bfr[2];
#pragma unroll
      for (int mt = 0; mt < MT; ++mt)
        af[mt] = __builtin_bit_cast(bf16x8,
            *(const uint4*)&As[wm + mt * 16 + l15][ks * 32 + quad * 8]);
#pragma unroll
      for (int nt = 0; nt < 2; ++nt)
        bfr[nt] = __builtin_bit_cast(bf16x8,
            *(const uint4*)&Bs[wn + nt * 16 + l15][ks * 32 + quad * 8]);
#pragma unroll
      for (int mt = 0; mt < MT; ++mt)
#pragma unroll
        for (int nt = 0; nt < 2; ++nt)
          acc[mt][nt] = __builtin_amdgcn_mfma_f32_16x16x32_bf16(
              af[mt], bfr[nt], acc[mt][nt], 0, 0, 0);
    }
    __syncthreads();
  }
  float bv[2];
#pragma unroll
  for (int nt = 0; nt < 2; ++nt)
    bv[nt] = bias ? bias[n0 + wn + nt * 16 + l15] : 0.f;
#pragma unroll
  for (int mt = 0; mt < MT; ++mt) {
#pragma unroll
    for (int nt = 0; nt < 2; ++nt) {
#pragma unroll
      for (int reg = 0; reg < 4; ++reg) {
        int m = m0 + wm + mt * 16 + quad * 4 + reg;
        int n = n0 + wn + nt * 16 + l15;
        float v = acc[mt][nt][reg] + bv[nt];
        if constexpr (ACT == 1) v = gelu_f(v);
        if constexpr (RESM == 1)
          v += ((const float*)res)[(size_t)m * N + n];
        if constexpr (RESM == 2)
          v += b2f(((const unsigned short*)res)[(size_t)m * N + n]);
        if constexpr (OUTM == 0)
          ((unsigned short*)out)[(size_t)m * N + n] = f2b(v);
        if constexpr (OUTM == 1)
          T[(n - n0)][(m - m0)] = v;
        if constexpr (OUTM == 4)
          ((unsigned short*)out)[((size_t)(n >> 8) * 8192 + m) * 256 + (n & 255)] = f2b(v);
        if constexpr (OUTM == 5) {
          // offset-grid + coord pack. n = 2r + coord (interleaved weights).
          float val = tanhf(v) * (2.0f / 64.0f);
          int r = n >> 1, coord = n & 1;
          int rc = coord ? (r & 31) : (r >> 5);
          float ref = rc * (4.0f / 63.0f) - 1.0f;
          float pix = (val + ref + 1.0f) * 31.5f;
          float other = __shfl_xor(pix, 1, 64);   // partner lane has col coord
          if (coord == 0) {
            float rowp = pix, colp = other;
            float r0f = floorf(rowp), c0f = floorf(colp);
            float wr = rowp - r0f, wc = colp - c0f;
            int r0 = (int)r0f, c0 = (int)c0f;
            bool rv0 = ((unsigned)r0 < 64u), rv1 = ((unsigned)(r0 + 1) < 64u);
            bool cv0 = ((unsigned)c0 < 64u), cv1 = ((unsigned)(c0 + 1) < 64u);
            float4 w4;
            w4.x = (rv0 && cv0) ? (1.f - wr) * (1.f - wc) : 0.f;
            w4.y = (rv0 && cv1) ? (1.f - wr) * wc : 0.f;
            w4.z = (rv1 && cv0) ? wr * (1.f - wc) : 0.f;
            w4.w = (rv1 && cv1) ? wr * wc : 0.f;
            ((int*)out)[(size_t)m * 1024 + r] = r0 * 64 + c0;
            *(float4*)((float*)res + ((size_t)m * 1024 + r) * 4) = w4;
          }
        }
      }
    }
  }
  if constexpr (OUTM == 1) {
    __syncthreads();
    constexpr int SEGS = BM / 32;
    int units = 64 * SEGS;
    if (t < units) {
      int nl = t / SEGS, seg = t % SEGS;
      int bI = m0 >> 12, hw0 = m0 & 4095;
      float* op = (float*)out + ((size_t)bI * 256 + n0 + nl) * 4096 + hw0 + seg * 32;
#pragma unroll
      for (int k = 0; k < 32; ++k) op[k] = T[nl][seg * 32 + k];
    }
  }
}

// ---------------- fused depthwise chain: 3x (3x3 s2 p1) in one launch ------
// 64 blocks = (bg 0..3) x (cg 0..15, 8 channels each). Chain in LDS (40KB).
__global__ __launch_bounds__(256) void dwfused_kernel(
    const bf16* __restrict__ qb, const float* __restrict__ w1_,
    const float* __restrict__ w2_, const float* __restrict__ w3_,
    const float* __restrict__ bng, const float* __restrict__ bnb,
    const float* __restrict__ bnm, const float* __restrict__ bnv,
    bf16* __restrict__ dw3b)
{
  __shared__ float L1[1024][8];   // 32KB  (32x32 x 8ch)
  __shared__ float L2[256][8];    // 8KB   (16x16 x 8ch)
  int blk = blockIdx.x;
  int bg = blk >> 4, cg = blk & 15;
  int b = bg >> 1, g = bg & 1;
  int t = threadIdx.x;
  int cl = t & 7;
  int c127 = cg * 8 + cl;
  int choff = g * 128 + c127;
  float wreg[9];
  // ---- dw1: qb(64x64) -> L1(32x32) ----
#pragma unroll
  for (int k = 0; k < 9; ++k) wreg[k] = w1_[c127 * 9 + k];
  for (int i = 0; i < 32; ++i) {
    int sp = (t >> 3) + i * 32;
    int oh = sp >> 5, ow = sp & 31;
    float acc = 0.f;
#pragma unroll
    for (int ky = 0; ky < 3; ++ky) {
      int ih = oh * 2 - 1 + ky;
      if ((unsigned)ih >= 64u) continue;
#pragma unroll
      for (int kx = 0; kx < 3; ++kx) {
        int iw = ow * 2 - 1 + kx;
        if ((unsigned)iw >= 64u) continue;
        acc += wreg[ky * 3 + kx] *
               cvt(qb[((size_t)b * 4096 + ih * 64 + iw) * 256 + choff]);
      }
    }
    L1[sp][cl] = acc;
  }
  __syncthreads();
  // ---- dw2: L1(32x32) -> L2(16x16) ----
#pragma unroll
  for (int k = 0; k < 9; ++k) wreg[k] = w2_[c127 * 9 + k];
  for (int i = 0; i < 8; ++i) {
    int sp = (t >> 3) + i * 32;
    int oh = sp >> 4, ow = sp & 15;
    float acc = 0.f;
#pragma unroll
    for (int ky = 0; ky < 3; ++ky) {
      int ih = oh * 2 - 1 + ky;
      if ((unsigned)ih >= 32u) continue;
#pragma unroll
      for (int kx = 0; kx < 3; ++kx) {
        int iw = ow * 2 - 1 + kx;
        if ((unsigned)iw >= 32u) continue;
        acc += wreg[ky * 3 + kx] * L1[ih * 32 + iw][cl];
      }
    }
    L2[sp][cl] = acc;
  }
  __syncthreads();
  // ---- dw3: L2(16x16) -> dw3b(8x8) + BN + GELU ----
#pragma unroll
  for (int k = 0; k < 9; ++k) wreg[k] = w3_[c127 * 9 + k];
  float sc = rsqrtf(bnv[c127] + 1e-5f) * bng[c127];
  float mb = bnm[c127], bb2 = bnb[c127];
  for (int i = 0; i < 2; ++i) {
    int sp = (t >> 3) + i * 32;
    int oh = sp >> 3, ow = sp & 7;
    float acc = 0.f;
#pragma unroll
    for (int ky = 0; ky < 3; ++ky) {
      int ih = oh * 2 - 1 + ky;
      if ((unsigned)ih >= 16u) continue;
#pragma unroll
      for (int kx = 0; kx < 3; ++kx) {
        int iw = ow * 2 - 1 + kx;
        if ((unsigned)iw >= 16u) continue;
        acc += wreg[ky * 3 + kx] * L2[ih * 16 + iw][cl];
      }
    }
    acc = (acc - mb) * sc + bb2;
    acc = gelu_f(acc);
    dw3b[((size_t)bg * 64 + sp) * 128 + c127] = __float2bfloat16(acc);
  }
}

// ---------------- attn helpers: pipelined bilinear gather (precomputed) ----
__device__ __forceinline__ void gather_issue(
    int rc0, int b, int nw, int gr_r, int choff,
    const int* __restrict__ goff, const float* __restrict__ gwt,
    const unsigned short* __restrict__ Kimg, const unsigned short* __restrict__ Vimg,
    uint4* kc, uint4* vc, f32x4* wv)
{
#pragma unroll
  for (int g = 0; g < 2; ++g) {
    size_t cbase = ((size_t)(b * 2 + g) * 64 + nw) * 1024 + rc0 + gr_r;
    int base = goff[cbase];
    wv[g] = *(const f32x4*)(gwt + cbase * 4);
    int o00 = min(max(base, 0), 4095);
    int o01 = min(max(base + 1, 0), 4095);
    int o10 = min(max(base + 64, 0), 4095);
    int o11 = min(max(base + 65, 0), 4095);
    size_t pb = ((size_t)g * 8192 + (size_t)b * 4096) * 256 + choff;
    kc[g * 4 + 0] = *(const uint4*)(Kimg + pb + (size_t)o00 * 256);
    vc[g * 4 + 0] = *(const uint4*)(Vimg + pb + (size_t)o00 * 256);
    kc[g * 4 + 1] = *(const uint4*)(Kimg + pb + (size_t)o01 * 256);
    vc[g * 4 + 1] = *(const uint4*)(Vimg + pb + (size_t)o01 * 256);
    kc[g * 4 + 2] = *(const uint4*)(Kimg + pb + (size_t)o10 * 256);
    vc[g * 4 + 2] = *(const uint4*)(Vimg + pb + (size_t)o10 * 256);
    kc[g * 4 + 3] = *(const uint4*)(Kimg + pb + (size_t)o11 * 256);
    vc[g * 4 + 3] = *(const uint4*)(Vimg + pb + (size_t)o11 * 256);
  }
}

// ---------------- MFMA fused deformable window attention (pipelined) -------
__global__ __launch_bounds__(256) void attn_kernel(
    const bf16* __restrict__ qbuf, const unsigned short* __restrict__ Kimg,
    const unsigned short* __restrict__ Vimg, const int* __restrict__ goff,
    const float* __restrict__ gwt, const float* __restrict__ vbv,
    const float* __restrict__ pe, bf16* __restrict__ aout)
{
  __shared__ unsigned short ks[2][64][40];
  __shared__ unsigned short vs[2][32][72];
  __shared__ unsigned short PsQs[64][72];
  __shared__ unsigned short pesb[70][72];

  int blk = blockIdx.x;
  int b = blk & 1, head = (blk >> 1) & 7, nw = blk >> 4;
  int wh = nw >> 3, ww = nw & 7;
  int t = threadIdx.x;
  int lane = t & 63, w = t >> 6;
  int l15 = lane & 15, quad = lane >> 4;
  int qc0 = head * 32;
  int gr_r = t >> 2, gr_seg = t & 3;
  int choff = qc0 + gr_seg * 8;

  {
    int qt = t >> 2, oct = t & 3;
    int h = wh * 8 + (qt >> 3), wcol = ww * 8 + (qt & 7);
    const bf16* src = qbuf + ((size_t)b * 4096 + h * 64 + wcol) * 256 + qc0 + oct * 8;
    U16x8 u; u.u4 = *(const uint4*)src;
    U16x8 o;
#pragma unroll
    for (int j = 0; j < 8; ++j) o.us[j] = f2b(b2f(u.us[j]) * 0.0625f);
    *(uint4*)&PsQs[qt][oct * 8] = o.u4;
  }
  int ry0 = 56 - wh * 8, rx0 = 56 - ww * 8;
  for (int i = t; i < 70 * 70; i += 256) {
    int yy = i / 70, xx = i % 70;
    pesb[yy][xx] = f2b(pe[(size_t)head * 16129 + (ry0 + yy) * 127 + rx0 + xx]);
  }

  uint4 kc[8], vc[8];
  f32x4 wv[2];
  gather_issue(0, b, nw, gr_r, choff, goff, gwt, Kimg, Vimg, kc, vc, wv);
  {
    float aK[8] = {0,0,0,0,0,0,0,0}, aV[8] = {0,0,0,0,0,0,0,0};
#pragma unroll
    for (int g = 0; g < 2; ++g)
#pragma unroll
      for (int c4 = 0; c4 < 4; ++c4) {
        U16x8 ku, vu; ku.u4 = kc[g * 4 + c4]; vu.u4 = vc[g * 4 + c4];
        float wvv = wv[g][c4];
#pragma unroll
        for (int j = 0; j < 8; ++j) { aK[j] += wvv * b2f(ku.us[j]); aV[j] += wvv * b2f(vu.us[j]); }
      }
    U16x8 ok;
#pragma unroll
    for (int j = 0; j < 8; ++j) ok.us[j] = f2b(aK[j]);
    *(uint4*)&ks[0][gr_r][gr_seg * 8] = ok.u4;
#pragma unroll
    for (int j = 0; j < 8; ++j) {
      int row = gr_seg * 8 + j;
      vs[0][row][gr_r ^ (((row >> 3) & 3) * 8)] = f2b(aV[j]);
    }
  }
  __syncthreads();

  bf16x8 aQ;
  {
    uint4 u = *(const uint4*)&PsQs[w * 16 + l15][quad * 8];
    aQ = __builtin_bit_cast(bf16x8, u);
  }
  float l[4] = {0.f, 0.f, 0.f, 0.f};
  f32x4 oacc[2];
  oacc[0] = (f32x4){0.f, 0.f, 0.f, 0.f};
  oacc[1] = (f32x4){0.f, 0.f, 0.f, 0.f};

  for (int c = 0; c < 16; ++c) {
    if (c) __syncthreads();
    int cur = c & 1, rc0 = c * 64;
    if (c < 15)
      gather_issue(rc0 + 64, b, nw, gr_r, choff, goff, gwt, Kimg, Vimg, kc, vc, wv);

    f32x4 s[4];
#pragma unroll
    for (int nt = 0; nt < 4; ++nt) {
      uint4 u = *(const uint4*)&ks[cur][nt * 16 + l15][quad * 8];
      bf16x8 bK = __builtin_bit_cast(bf16x8, u);
      f32x4 z = (f32x4){0.f, 0.f, 0.f, 0.f};
      s[nt] = __builtin_amdgcn_mfma_f32_16x16x32_bf16(aQ, bK, z, 0, 0, 0);
    }
#pragma unroll
    for (int nt = 0; nt < 4; ++nt) {
      int rg_ = nt * 16 + l15;
      int rrow = (rc0 + rg_) >> 5, rcol = rg_ & 31;
#pragma unroll
      for (int reg = 0; reg < 4; ++reg) {
        int q = w * 16 + quad * 4 + reg;
        s[nt][reg] += b2f(pesb[2 * rrow + 7 - (q >> 3)][2 * rcol + 7 - (q & 7)]);
      }
    }
#pragma unroll
    for (int reg = 0; reg < 4; ++reg) {
      float ps = 0.f;
#pragma unroll
      for (int nt = 0; nt < 4; ++nt) {
        float p = __expf(s[nt][reg]);
        PsQs[w * 16 + quad * 4 + reg][nt * 16 + l15] = f2b(p);
        ps += p;
      }
      ps += __shfl_xor(ps, 1, 64);
      ps += __shfl_xor(ps, 2, 64);
      ps += __shfl_xor(ps, 4, 64);
      ps += __shfl_xor(ps, 8, 64);
      l[reg] += ps;
    }
#pragma unroll
    for (int kst = 0; kst < 2; ++kst) {
      uint4 up = *(const uint4*)&PsQs[w * 16 + l15][kst * 32 + quad * 8];
      bf16x8 pA = __builtin_bit_cast(bf16x8, up);
#pragma unroll
      for (int nt2 = 0; nt2 < 2; ++nt2) {
        int row = nt2 * 16 + l15;
        int cbase = (kst * 32 + quad * 8) ^ (((row >> 3) & 3) * 8);
        uint4 uv = *(const uint4*)&vs[cur][row][cbase];
        bf16x8 vB = __builtin_bit_cast(bf16x8, uv);
        oacc[nt2] = __builtin_amdgcn_mfma_f32_16x16x32_bf16(pA, vB, oacc[nt2], 0, 0, 0);
      }
    }
    if (c < 15) {
      float aK[8] = {0,0,0,0,0,0,0,0}, aV[8] = {0,0,0,0,0,0,0,0};
#pragma unroll
      for (int g = 0; g < 2; ++g)
#pragma unroll
        for (int c4 = 0; c4 < 4; ++c4) {
          U16x8 ku, vu; ku.u4 = kc[g * 4 + c4]; vu.u4 = vc[g * 4 + c4];
          float wvv = wv[g][c4];
#pragma unroll
          for (int j = 0; j < 8; ++j) { aK[j] += wvv * b2f(ku.us[j]); aV[j] += wvv * b2f(vu.us[j]); }
        }
      int nxt = cur ^ 1;
      U16x8 ok;
#pragma unroll
      for (int j = 0; j < 8; ++j) ok.us[j] = f2b(aK[j]);
      *(uint4*)&ks[nxt][gr_r][gr_seg * 8] = ok.u4;
#pragma unroll
      for (int j = 0; j < 8; ++j) {
        int row = gr_seg * 8 + j;
        vs[nxt][row][gr_r ^ (((row >> 3) & 3) * 8)] = f2b(aV[j]);
      }
    }
  }
#pragma unroll
  for (int nt2 = 0; nt2 < 2; ++nt2) {
    float vbias = vbv[qc0 + nt2 * 16 + l15];
#pragma unroll
    for (int reg = 0; reg < 4; ++reg) {
      int q = w * 16 + quad * 4 + reg;
      size_t p = (size_t)b * 4096 + (wh * 8 + (q >> 3)) * 64 + ww * 8 + (q & 7);
      aout[p * 256 + qc0 + nt2 * 16 + l15] =
          __float2bfloat16(oacc[nt2][reg] / l[reg] + vbias);
    }
  }
}

// ---------------------------------------------------------------------------
extern "C" void kernel_launch(void* const* d_in, const int* in_sizes, int n_in,
                              void* d_out, int out_size, void* d_ws, size_t ws_size,
                              hipStream_t stream) {
  (void)in_sizes; (void)n_in; (void)out_size; (void)ws_size;
  const float* x     = (const float*)d_in[0];
  const float* ln1g  = (const float*)d_in[1];
  const float* ln1b  = (const float*)d_in[2];
  const float* q_w   = (const float*)d_in[3];
  const float* q_b   = (const float*)d_in[4];
  const float* k_w   = (const float*)d_in[5];
  const float* k_b   = (const float*)d_in[6];
  const float* v_w   = (const float*)d_in[7];
  const float* v_b   = (const float*)d_in[8];
  const float* off1w = (const float*)d_in[9];
  const float* off2w = (const float*)d_in[10];
  const float* off3w = (const float*)d_in[11];
  const float* bng   = (const float*)d_in[12];
  const float* bnb   = (const float*)d_in[13];
  const float* bnm   = (const float*)d_in[14];
  const float* bnv   = (const float*)d_in[15];
  const float* off4w = (const float*)d_in[16];
  const float* pe    = (const float*)d_in[17];
  const float* pjw   = (const float*)d_in[18];
  const float* pjb   = (const float*)d_in[19];
  const float* ln2g  = (const float*)d_in[20];
  const float* ln2b  = (const float*)d_in[21];
  const float* w1    = (const float*)d_in[22];
  const float* b1    = (const float*)d_in[23];
  const float* w2    = (const float*)d_in[24];
  const float* b2    = (const float*)d_in[25];
  (void)k_b;
  float* outp = (float*)d_out;

  char* W = (char*)d_ws;
  bf16*  xa    = (bf16*) (W + 0);          // [8192][256]; reused as aout/xm
  bf16*  dw3b  = (bf16*) (W + 11010048);   // [4][64][128] bf16
  bf16*  qkv   = (bf16*) (W + 13238272);   // [5][8192][256]
  bf16*  qb    = qkv;
  bf16*  Kimg  = qkv + 2097152;
  bf16*  Vimg  = qkv + 3 * 2097152;
  bf16*  x2    = (bf16*) (W + 34209792);
  float* xnhwc = (float*)(W + 38404096);
  unsigned short* wqkv   = (unsigned short*)(W + 46792704);
  float*          bqkv   = (float*)         (W + 47448064);
  unsigned short* wproj  = (unsigned short*)(W + 47453184);
  unsigned short* wmlp1  = (unsigned short*)(W + 47584256);
  unsigned short* wmlp2  = (unsigned short*)(W + 48108544);
  unsigned short* woff4i = (unsigned short*)(W + 48632832);
  int*   goff  = (int*)  (W + 49157120);
  float* gwt   = (float*)(W + 50205696);
  bf16*  aout = xa;
  bf16*  xm   = xa;
  bf16*  hdn  = Kimg;

  // 1. setup: LN1 + all weight prep in one launch
  setup_kernel<<<4869, 256, 0, stream>>>(
      x, ln1g, ln1b, q_w, q_b, k_w, v_w, pjw, w1, w2, off4w,
      xa, xnhwc, wqkv, bqkv, wproj, wmlp1, wmlp2, woff4i);
  // 2. fused QKV GEMM: N=1280 -> q | Kimg | Vimg
  mgemm_kernel<4, 0, 0, 128><<<dim3(20, 64), 256, 0, stream>>>(
      xa, wqkv, bqkv, nullptr, qkv, 1280, 256, 256, 256);
  // 3. fused depthwise chain (one launch, LDS intermediates)
  dwfused_kernel<<<64, 256, 0, stream>>>(qb, off1w, off2w, off3w,
                                         bng, bnb, bnm, bnv, dw3b);
  // 4. offset head GEMM + tanh/grid + coord pack (OUTM=5)
  mgemm_kernel<5, 0, 0, 128><<<dim3(32, 2), 256, 0, stream>>>(
      dw3b, woff4i, nullptr, (const void*)gwt, goff, 2048, 128, 128, 128);
  // 5. fused attention (pipelined gather from precomputed offsets/weights)
  attn_kernel<<<1024, 256, 0, stream>>>(
      qb, (const unsigned short*)Kimg, (const unsigned short*)Vimg,
      goff, gwt, v_b, pe, aout);
  // 6. proj + residual(x_nhwc f32) -> x2 NHWC bf16
  mgemm_kernel<0, 1, 0, 64><<<dim3(4, 128), 256, 0, stream>>>(
      aout, wproj, pjb, (const void*)xnhwc, x2, 256, 256, 256, 256);
  // 7. LN2 -> xm
  ln2_kernel<<<256, 256, 0, stream>>>(x2, ln2g, ln2b, xm);
  // 8. MLP1 + GELU -> hdn
  mgemm_kernel<0, 0, 1, 128><<<dim3(16, 64), 256, 0, stream>>>(
      xm, wmlp1, b1, nullptr, hdn, 1024, 256, 256, 256);
  // 9. MLP2 + residual(x2) -> f32 NCHW d_out via LDS transpose
  mgemm_kernel<1, 2, 0, 64><<<dim3(4, 128), 256, 0, stream>>>(
      hdn, wmlp2, b2, (const void*)x2, outp, 256, 1024, 1024, 1024);
}

// Round 12
// 313.347 us; speedup vs baseline: 1.1255x; 1.1255x over previous
//
#include <hip/hip_runtime.h>
#include <hip/hip_bf16.h>
#include <math.h>

// CBiAFormerBlock fused implementation, round 12.
// Post-mortem r11 (353us, REGRESSION vs r10's 316): dwfused_kernel collapsed
// grid parallelism (64 blocks on 256 CUs, serial 3-stage LDS chain ~40us vs
// ~8us for the three parallel dwconv launches). Launch-overhead theory for
// the non-attn family is disconfirmed as the dominant term.
// r12 = r11 with dwfused REVERTED to the three r10 dwconv launches; the two
// parallelism-preserving fusions are kept:
//  - setup_kernel = LN1 (blocks 0..255) UNION weight prep (256..4868).
//  - offgrid mgemm OUTM=5 absorbs packc (interleaved off4 weights, shfl_xor
//    pairs row/col coords; even lanes emit goff/gwt).
// attn/proj/ln2/mlp1/mlp2/qkv byte-identical to r10/r11.

typedef __hip_bfloat16 bf16;
typedef __bf16 bf16x8 __attribute__((ext_vector_type(8)));
typedef float f32x4 __attribute__((ext_vector_type(4)));

union U16x8 { uint4 u4; unsigned short us[8]; };

__device__ __forceinline__ float cvt(float x) { return x; }
__device__ __forceinline__ float cvt(bf16 x) { return __bfloat162float(x); }
__device__ __forceinline__ float b2f(unsigned short u) {
  union { float f; unsigned int v; } x; x.v = ((unsigned int)u) << 16; return x.f;
}
__device__ __forceinline__ unsigned short f2b(float f) {
  bf16 h = __float2bfloat16(f);
  return *reinterpret_cast<unsigned short*>(&h);
}
__device__ __forceinline__ float gelu_f(float x) {
  return 0.5f * x * (1.0f + erff(x * 0.7071067811865475f));
}
__device__ __forceinline__ void stout(float* p, float v) { *p = v; }
__device__ __forceinline__ void stout(bf16* p, float v) { *p = __float2bfloat16(v); }

// ---------------- setup: LN1 (blocks 0..255) UNION weight prep (256..4868) --
__global__ __launch_bounds__(256) void setup_kernel(
    const float* __restrict__ x, const float* __restrict__ g,
    const float* __restrict__ bta,
    const float* __restrict__ q_w, const float* __restrict__ q_b,
    const float* __restrict__ k_w, const float* __restrict__ v_w,
    const float* __restrict__ pjw, const float* __restrict__ w1,
    const float* __restrict__ w2, const float* __restrict__ off4w,
    bf16* __restrict__ out, float* __restrict__ xnhwc,
    unsigned short* __restrict__ wqkv, float* __restrict__ bqkv,
    unsigned short* __restrict__ wproj, unsigned short* __restrict__ wmlp1,
    unsigned short* __restrict__ wmlp2, unsigned short* __restrict__ woff4i)
{
  __shared__ float s1[8][32], s2[8][32];
  __shared__ unsigned short tb[32][264];
  int bid = blockIdx.x;
  int t = threadIdx.x;
  if (bid < 256) {
    int pos = t & 31, cs = t >> 5;
    int p = bid * 32 + pos;
    int bb = p >> 12, hw = p & 4095;
    const float* xp = x + (size_t)bb * 256 * 4096 + hw;
    float vloc[32];
    float sum = 0.f, ss = 0.f;
#pragma unroll
    for (int i = 0; i < 32; ++i) {
      float v = xp[(size_t)(cs * 32 + i) * 4096];
      vloc[i] = v; sum += v; ss += v * v;
    }
    s1[cs][pos] = sum; s2[cs][pos] = ss;
    {
      float* xo = xnhwc + (size_t)p * 256 + cs * 32;
#pragma unroll
      for (int qd = 0; qd < 8; ++qd)
        *(float4*)(xo + qd * 4) = make_float4(vloc[qd*4], vloc[qd*4+1],
                                              vloc[qd*4+2], vloc[qd*4+3]);
    }
    __syncthreads();
    if (cs == 0) {
      float S = 0.f, Q = 0.f;
#pragma unroll
      for (int i = 0; i < 8; ++i) { S += s1[i][pos]; Q += s2[i][pos]; }
      float mu = S * (1.f / 256.f);
      float var = Q * (1.f / 256.f) - mu * mu;
      s1[0][pos] = mu;
      s2[0][pos] = rsqrtf(var + 1e-5f);
    }
    __syncthreads();
    float mu = s1[0][pos], rs = s2[0][pos];
#pragma unroll
    for (int i = 0; i < 32; ++i) {
      int c = cs * 32 + i;
      tb[pos][c] = f2b((vloc[i] - mu) * rs * g[c] + bta[c]);
    }
    __syncthreads();
    int px = t >> 3, grp = t & 7;
    bf16* op = out + ((size_t)bid * 32 + px) * 256 + grp * 32;
#pragma unroll
    for (int q = 0; q < 4; ++q)
      *(uint4*)(op + q * 8) = *(const uint4*)&tb[px][grp * 32 + q * 8];
  } else {
    int idx = (bid - 256) * 256 + t;
    const int S0 = 1280 * 256;
    const int S1 = S0 + 1280;
    const int S2 = S1 + 256 * 256;
    const int S3 = S2 + 1024 * 256;
    const int S4 = S3 + 256 * 1024;
    const int S5 = S4 + 2048 * 128;
    if (idx < S0) {
      int n = idx >> 8, c = idx & 255;
      float v;
      if (n < 256)       v = q_w[n * 256 + c];
      else if (n < 512)  v = (c < 128)  ? k_w[(n - 256) * 256 + c] : 0.f;
      else if (n < 768)  v = (c >= 128) ? k_w[(n - 512) * 256 + c] : 0.f;
      else if (n < 1024) v = (c < 128)  ? v_w[(n - 768) * 256 + c] : 0.f;
      else               v = (c >= 128) ? v_w[(n - 1024) * 256 + c] : 0.f;
      wqkv[idx] = f2b(v);
    } else if (idx < S1) {
      int n = idx - S0;
      bqkv[n] = (n < 256) ? q_b[n] : 0.f;
    } else if (idx < S2) {
      wproj[idx - S1] = f2b(pjw[idx - S1]);
    } else if (idx < S3) {
      wmlp1[idx - S2] = f2b(w1[idx - S2]);
    } else if (idx < S4) {
      wmlp2[idx - S3] = f2b(w2[idx - S3]);
    } else if (idx < S5) {
      int kk = idx - S4;
      int n = kk >> 7, c = kk & 127;
      // interleaved: n = 2r + coord  <-  off4w row coord*1024 + r
      woff4i[kk] = f2b(off4w[((size_t)((n & 1) * 1024 + (n >> 1))) * 128 + c]);
    }
  }
}

// ---------------- LN2: NHWC bf16 in -> NHWC bf16 out -----------------------
__global__ __launch_bounds__(256) void ln2_kernel(
    const bf16* __restrict__ xin, const float* __restrict__ g,
    const float* __restrict__ bta, bf16* __restrict__ out)
{
  __shared__ float sa[8][32], sb[8][32];
  __shared__ float mu_s[32], rs_s[32];
  int t = threadIdx.x;
  int px = t >> 3, grp = t & 7;
  size_t p = (size_t)blockIdx.x * 32 + px;
  const bf16* xp = xin + p * 256 + grp * 32;
  float v[32]; float sum = 0.f, ss = 0.f;
#pragma unroll
  for (int q = 0; q < 4; ++q) {
    U16x8 u; u.u4 = *(const uint4*)(xp + q * 8);
#pragma unroll
    for (int j = 0; j < 8; ++j) {
      float f = b2f(u.us[j]); v[q * 8 + j] = f; sum += f; ss += f * f;
    }
  }
  sa[grp][px] = sum; sb[grp][px] = ss;
  __syncthreads();
  if (t < 32) {
    float S = 0.f, Q = 0.f;
#pragma unroll
    for (int i = 0; i < 8; ++i) { S += sa[i][t]; Q += sb[i][t]; }
    float mu = S * (1.f / 256.f);
    mu_s[t] = mu;
    rs_s[t] = rsqrtf(Q * (1.f / 256.f) - mu * mu + 1e-5f);
  }
  __syncthreads();
  float mu = mu_s[px], rs = rs_s[px];
  bf16* op = out + p * 256 + grp * 32;
#pragma unroll
  for (int q = 0; q < 4; ++q) {
    U16x8 o;
#pragma unroll
    for (int j = 0; j < 8; ++j) {
      int c = grp * 32 + q * 8 + j;
      o.us[j] = f2b((v[q * 8 + j] - mu) * rs * g[c] + bta[c]);
    }
    *(uint4*)(op + q * 8) = o.u4;
  }
}

// ---------------- MFMA GEMM (NHWC): out[p][o] = sum_c A[p][c] W[o][c] ------
// OUTM: 0 bf16 NHWC; 1 f32 NCHW via LDS transpose; 4 grouped-QKV;
//       5 offset-grid head + coord pack (out=goff int32, res=gwt float4).
// RESM: 0 none; 1 f32 NHWC; 2 bf16 NHWC. ACT: 1 exact GELU.
template<int OUTM, int RESM, int ACT, int BM>
__global__ __launch_bounds__(256) void mgemm_kernel(
    const bf16* __restrict__ A, const unsigned short* __restrict__ Bw,
    const float* __restrict__ bias, const void* __restrict__ res,
    void* __restrict__ out, int N, int K, int lda, int ldb)
{
  constexpr int MT = BM / 32;
  constexpr int AB_BYTES = (BM + 64) * 72 * 2;
  constexpr int T_LD = BM + 5;
  constexpr int T_BYTES = 64 * T_LD * 4;
  constexpr int SH_BYTES = (OUTM == 1 && T_BYTES > AB_BYTES) ? T_BYTES : AB_BYTES;
  __shared__ __attribute__((aligned(16))) char shraw[SH_BYTES];
  auto As = reinterpret_cast<unsigned short(*)[72]>(shraw);
  auto Bs = reinterpret_cast<unsigned short(*)[72]>(shraw + BM * 72 * 2);
  float (*T)[T_LD] = reinterpret_cast<float(*)[T_LD]>(shraw);

  int t = threadIdx.x;
  int m0 = blockIdx.y * BM, n0 = blockIdx.x * 64;
  int lane = t & 63, w = t >> 6;
  int l15 = lane & 15, quad = lane >> 4;
  int wm = (w >> 1) * (BM / 2), wn = (w & 1) * 32;
  f32x4 acc[MT][2];
#pragma unroll
  for (int mt = 0; mt < MT; ++mt)
#pragma unroll
    for (int nt = 0; nt < 2; ++nt) acc[mt][nt] = (f32x4){0.f, 0.f, 0.f, 0.f};

  for (int k0 = 0; k0 < K; k0 += 64) {
#pragma unroll
    for (int i = 0; i < MT; ++i) {
      int idx = t + i * 256;
      int m = idx >> 3, oc = (idx & 7) * 8;
      *(uint4*)&As[m][oc] = *(const uint4*)(A + (size_t)(m0 + m) * lda + k0 + oc);
    }
#pragma unroll
    for (int i = 0; i < 2; ++i) {
      int idx = t + i * 256;
      int n = idx >> 3, oc = (idx & 7) * 8;
      *(uint4*)&Bs[n][oc] = *(const uint4*)(Bw + (size_t)(n0 + n) * ldb + k0 + oc);
    }
    __syncthreads();
#pragma unroll
    for (int ks = 0; ks < 2; ++ks) {
      bf16x8 af[MT], bfr[2];
#pragma unroll
      for (int mt = 0; mt < MT; ++mt)
        af[mt] = __builtin_bit_cast(bf16x8,
            *(const uint4*)&As[wm + mt * 16 + l15][ks * 32 + quad * 8]);
#pragma unroll
      for (int nt = 0; nt < 2; ++nt)
        bfr[nt] = __builtin_bit_cast(bf16x8,
            *(const uint4*)&Bs[wn + nt * 16 + l15][ks * 32 + quad * 8]);
#pragma unroll
      for (int mt = 0; mt < MT; ++mt)
#pragma unroll
        for (int nt = 0; nt < 2; ++nt)
          acc[mt][nt] = __builtin_amdgcn_mfma_f32_16x16x32_bf16(
              af[mt], bfr[nt], acc[mt][nt], 0, 0, 0);
    }
    __syncthreads();
  }
  float bv[2];
#pragma unroll
  for (int nt = 0; nt < 2; ++nt)
    bv[nt] = bias ? bias[n0 + wn + nt * 16 + l15] : 0.f;
#pragma unroll
  for (int mt = 0; mt < MT; ++mt) {
#pragma unroll
    for (int nt = 0; nt < 2; ++nt) {
#pragma unroll
      for (int reg = 0; reg < 4; ++reg) {
        int m = m0 + wm + mt * 16 + quad * 4 + reg;
        int n = n0 + wn + nt * 16 + l15;
        float v = acc[mt][nt][reg] + bv[nt];
        if constexpr (ACT == 1) v = gelu_f(v);
        if constexpr (RESM == 1)
          v += ((const float*)res)[(size_t)m * N + n];
        if constexpr (RESM == 2)
          v += b2f(((const unsigned short*)res)[(size_t)m * N + n]);
        if constexpr (OUTM == 0)
          ((unsigned short*)out)[(size_t)m * N + n] = f2b(v);
        if constexpr (OUTM == 1)
          T[(n - n0)][(m - m0)] = v;
        if constexpr (OUTM == 4)
          ((unsigned short*)out)[((size_t)(n >> 8) * 8192 + m) * 256 + (n & 255)] = f2b(v);
        if constexpr (OUTM == 5) {
          float val = tanhf(v) * (2.0f / 64.0f);
          int r = n >> 1, coord = n & 1;
          int rc = coord ? (r & 31) : (r >> 5);
          float ref = rc * (4.0f / 63.0f) - 1.0f;
          float pix = (val + ref + 1.0f) * 31.5f;
          float other = __shfl_xor(pix, 1, 64);
          if (coord == 0) {
            float rowp = pix, colp = other;
            float r0f = floorf(rowp), c0f = floorf(colp);
            float wr = rowp - r0f, wc = colp - c0f;
            int r0 = (int)r0f, c0 = (int)c0f;
            bool rv0 = ((unsigned)r0 < 64u), rv1 = ((unsigned)(r0 + 1) < 64u);
            bool cv0 = ((unsigned)c0 < 64u), cv1 = ((unsigned)(c0 + 1) < 64u);
            float4 w4;
            w4.x = (rv0 && cv0) ? (1.f - wr) * (1.f - wc) : 0.f;
            w4.y = (rv0 && cv1) ? (1.f - wr) * wc : 0.f;
            w4.z = (rv1 && cv0) ? wr * (1.f - wc) : 0.f;
            w4.w = (rv1 && cv1) ? wr * wc : 0.f;
            ((int*)out)[(size_t)m * 1024 + r] = r0 * 64 + c0;
            *(float4*)((float*)res + ((size_t)m * 1024 + r) * 4) = w4;
          }
        }
      }
    }
  }
  if constexpr (OUTM == 1) {
    __syncthreads();
    constexpr int SEGS = BM / 32;
    int units = 64 * SEGS;
    if (t < units) {
      int nl = t / SEGS, seg = t % SEGS;
      int bI = m0 >> 12, hw0 = m0 & 4095;
      float* op = (float*)out + ((size_t)bI * 256 + n0 + nl) * 4096 + hw0 + seg * 32;
#pragma unroll
      for (int k = 0; k < 32; ++k) op[k] = T[nl][seg * 32 + k];
    }
  }
}

// ---------------- depthwise 3x3 stride-2 pad-1 conv, NHWC-128 --------------
template<typename TI, typename TO, int IC>
__global__ __launch_bounds__(256) void dwconv_kernel(
    const TI* __restrict__ in, const float* __restrict__ wgt,
    TO* __restrict__ out, int Hi, int Wi, int Ho, int Wo, int fuse,
    const float* __restrict__ bg_, const float* __restrict__ bb_,
    const float* __restrict__ bm_, const float* __restrict__ bv_)
{
  int idx = blockIdx.x * 256 + threadIdx.x;
  int c = idx & 127;
  int pp = idx >> 7;
  int ow = pp % Wo, oh = (pp / Wo) % Ho, bgi = pp / (Wo * Ho);
  const TI* ip;
  if constexpr (IC == 256)
    ip = in + ((size_t)(bgi >> 1) * 4096) * 256 + (bgi & 1) * 128 + c;
  else
    ip = in + ((size_t)bgi * Hi * Wi) * 128 + c;
  float acc = 0.f;
#pragma unroll
  for (int ky = 0; ky < 3; ++ky) {
    int ih = oh * 2 - 1 + ky;
    if ((unsigned)ih >= (unsigned)Hi) continue;
#pragma unroll
    for (int kx = 0; kx < 3; ++kx) {
      int iw = ow * 2 - 1 + kx;
      if ((unsigned)iw >= (unsigned)Wi) continue;
      acc += wgt[c * 9 + ky * 3 + kx] * cvt(ip[(size_t)(ih * Wi + iw) * IC]);
    }
  }
  if (fuse) {
    acc = (acc - bm_[c]) * rsqrtf(bv_[c] + 1e-5f) * bg_[c] + bb_[c];
    acc = gelu_f(acc);
  }
  stout(out + idx, acc);
}

// ---------------- attn helpers: pipelined bilinear gather (precomputed) ----
__device__ __forceinline__ void gather_issue(
    int rc0, int b, int nw, int gr_r, int choff,
    const int* __restrict__ goff, const float* __restrict__ gwt,
    const unsigned short* __restrict__ Kimg, const unsigned short* __restrict__ Vimg,
    uint4* kc, uint4* vc, f32x4* wv)
{
#pragma unroll
  for (int g = 0; g < 2; ++g) {
    size_t cbase = ((size_t)(b * 2 + g) * 64 + nw) * 1024 + rc0 + gr_r;
    int base = goff[cbase];
    wv[g] = *(const f32x4*)(gwt + cbase * 4);
    int o00 = min(max(base, 0), 4095);
    int o01 = min(max(base + 1, 0), 4095);
    int o10 = min(max(base + 64, 0), 4095);
    int o11 = min(max(base + 65, 0), 4095);
    size_t pb = ((size_t)g * 8192 + (size_t)b * 4096) * 256 + choff;
    kc[g * 4 + 0] = *(const uint4*)(Kimg + pb + (size_t)o00 * 256);
    vc[g * 4 + 0] = *(const uint4*)(Vimg + pb + (size_t)o00 * 256);
    kc[g * 4 + 1] = *(const uint4*)(Kimg + pb + (size_t)o01 * 256);
    vc[g * 4 + 1] = *(const uint4*)(Vimg + pb + (size_t)o01 * 256);
    kc[g * 4 + 2] = *(const uint4*)(Kimg + pb + (size_t)o10 * 256);
    vc[g * 4 + 2] = *(const uint4*)(Vimg + pb + (size_t)o10 * 256);
    kc[g * 4 + 3] = *(const uint4*)(Kimg + pb + (size_t)o11 * 256);
    vc[g * 4 + 3] = *(const uint4*)(Vimg + pb + (size_t)o11 * 256);
  }
}

// ---------------- MFMA fused deformable window attention (pipelined) -------
__global__ __launch_bounds__(256) void attn_kernel(
    const bf16* __restrict__ qbuf, const unsigned short* __restrict__ Kimg,
    const unsigned short* __restrict__ Vimg, const int* __restrict__ goff,
    const float* __restrict__ gwt, const float* __restrict__ vbv,
    const float* __restrict__ pe, bf16* __restrict__ aout)
{
  __shared__ unsigned short ks[2][64][40];
  __shared__ unsigned short vs[2][32][72];
  __shared__ unsigned short PsQs[64][72];
  __shared__ unsigned short pesb[70][72];

  int blk = blockIdx.x;
  int b = blk & 1, head = (blk >> 1) & 7, nw = blk >> 4;
  int wh = nw >> 3, ww = nw & 7;
  int t = threadIdx.x;
  int lane = t & 63, w = t >> 6;
  int l15 = lane & 15, quad = lane >> 4;
  int qc0 = head * 32;
  int gr_r = t >> 2, gr_seg = t & 3;
  int choff = qc0 + gr_seg * 8;

  {
    int qt = t >> 2, oct = t & 3;
    int h = wh * 8 + (qt >> 3), wcol = ww * 8 + (qt & 7);
    const bf16* src = qbuf + ((size_t)b * 4096 + h * 64 + wcol) * 256 + qc0 + oct * 8;
    U16x8 u; u.u4 = *(const uint4*)src;
    U16x8 o;
#pragma unroll
    for (int j = 0; j < 8; ++j) o.us[j] = f2b(b2f(u.us[j]) * 0.0625f);
    *(uint4*)&PsQs[qt][oct * 8] = o.u4;
  }
  int ry0 = 56 - wh * 8, rx0 = 56 - ww * 8;
  for (int i = t; i < 70 * 70; i += 256) {
    int yy = i / 70, xx = i % 70;
    pesb[yy][xx] = f2b(pe[(size_t)head * 16129 + (ry0 + yy) * 127 + rx0 + xx]);
  }

  uint4 kc[8], vc[8];
  f32x4 wv[2];
  gather_issue(0, b, nw, gr_r, choff, goff, gwt, Kimg, Vimg, kc, vc, wv);
  {
    float aK[8] = {0,0,0,0,0,0,0,0}, aV[8] = {0,0,0,0,0,0,0,0};
#pragma unroll
    for (int g = 0; g < 2; ++g)
#pragma unroll
      for (int c4 = 0; c4 < 4; ++c4) {
        U16x8 ku, vu; ku.u4 = kc[g * 4 + c4]; vu.u4 = vc[g * 4 + c4];
        float wvv = wv[g][c4];
#pragma unroll
        for (int j = 0; j < 8; ++j) { aK[j] += wvv * b2f(ku.us[j]); aV[j] += wvv * b2f(vu.us[j]); }
      }
    U16x8 ok;
#pragma unroll
    for (int j = 0; j < 8; ++j) ok.us[j] = f2b(aK[j]);
    *(uint4*)&ks[0][gr_r][gr_seg * 8] = ok.u4;
#pragma unroll
    for (int j = 0; j < 8; ++j) {
      int row = gr_seg * 8 + j;
      vs[0][row][gr_r ^ (((row >> 3) & 3) * 8)] = f2b(aV[j]);
    }
  }
  __syncthreads();

  bf16x8 aQ;
  {
    uint4 u = *(const uint4*)&PsQs[w * 16 + l15][quad * 8];
    aQ = __builtin_bit_cast(bf16x8, u);
  }
  float l[4] = {0.f, 0.f, 0.f, 0.f};
  f32x4 oacc[2];
  oacc[0] = (f32x4){0.f, 0.f, 0.f, 0.f};
  oacc[1] = (f32x4){0.f, 0.f, 0.f, 0.f};

  for (int c = 0; c < 16; ++c) {
    if (c) __syncthreads();
    int cur = c & 1, rc0 = c * 64;
    if (c < 15)
      gather_issue(rc0 + 64, b, nw, gr_r, choff, goff, gwt, Kimg, Vimg, kc, vc, wv);

    f32x4 s[4];
#pragma unroll
    for (int nt = 0; nt < 4; ++nt) {
      uint4 u = *(const uint4*)&ks[cur][nt * 16 + l15][quad * 8];
      bf16x8 bK = __builtin_bit_cast(bf16x8, u);
      f32x4 z = (f32x4){0.f, 0.f, 0.f, 0.f};
      s[nt] = __builtin_amdgcn_mfma_f32_16x16x32_bf16(aQ, bK, z, 0, 0, 0);
    }
#pragma unroll
    for (int nt = 0; nt < 4; ++nt) {
      int rg_ = nt * 16 + l15;
      int rrow = (rc0 + rg_) >> 5, rcol = rg_ & 31;
#pragma unroll
      for (int reg = 0; reg < 4; ++reg) {
        int q = w * 16 + quad * 4 + reg;
        s[nt][reg] += b2f(pesb[2 * rrow + 7 - (q >> 3)][2 * rcol + 7 - (q & 7)]);
      }
    }
#pragma unroll
    for (int reg = 0; reg < 4; ++reg) {
      float ps = 0.f;
#pragma unroll
      for (int nt = 0; nt < 4; ++nt) {
        float p = __expf(s[nt][reg]);
        PsQs[w * 16 + quad * 4 + reg][nt * 16 + l15] = f2b(p);
        ps += p;
      }
      ps += __shfl_xor(ps, 1, 64);
      ps += __shfl_xor(ps, 2, 64);
      ps += __shfl_xor(ps, 4, 64);
      ps += __shfl_xor(ps, 8, 64);
      l[reg] += ps;
    }
#pragma unroll
    for (int kst = 0; kst < 2; ++kst) {
      uint4 up = *(const uint4*)&PsQs[w * 16 + l15][kst * 32 + quad * 8];
      bf16x8 pA = __builtin_bit_cast(bf16x8, up);
#pragma unroll
      for (int nt2 = 0; nt2 < 2; ++nt2) {
        int row = nt2 * 16 + l15;
        int cbase = (kst * 32 + quad * 8) ^ (((row >> 3) & 3) * 8);
        uint4 uv = *(const uint4*)&vs[cur][row][cbase];
        bf16x8 vB = __builtin_bit_cast(bf16x8, uv);
        oacc[nt2] = __builtin_amdgcn_mfma_f32_16x16x32_bf16(pA, vB, oacc[nt2], 0, 0, 0);
      }
    }
    if (c < 15) {
      float aK[8] = {0,0,0,0,0,0,0,0}, aV[8] = {0,0,0,0,0,0,0,0};
#pragma unroll
      for (int g = 0; g < 2; ++g)
#pragma unroll
        for (int c4 = 0; c4 < 4; ++c4) {
          U16x8 ku, vu; ku.u4 = kc[g * 4 + c4]; vu.u4 = vc[g * 4 + c4];
          float wvv = wv[g][c4];
#pragma unroll
          for (int j = 0; j < 8; ++j) { aK[j] += wvv * b2f(ku.us[j]); aV[j] += wvv * b2f(vu.us[j]); }
        }
      int nxt = cur ^ 1;
      U16x8 ok;
#pragma unroll
      for (int j = 0; j < 8; ++j) ok.us[j] = f2b(aK[j]);
      *(uint4*)&ks[nxt][gr_r][gr_seg * 8] = ok.u4;
#pragma unroll
      for (int j = 0; j < 8; ++j) {
        int row = gr_seg * 8 + j;
        vs[nxt][row][gr_r ^ (((row >> 3) & 3) * 8)] = f2b(aV[j]);
      }
    }
  }
#pragma unroll
  for (int nt2 = 0; nt2 < 2; ++nt2) {
    float vbias = vbv[qc0 + nt2 * 16 + l15];
#pragma unroll
    for (int reg = 0; reg < 4; ++reg) {
      int q = w * 16 + quad * 4 + reg;
      size_t p = (size_t)b * 4096 + (wh * 8 + (q >> 3)) * 64 + ww * 8 + (q & 7);
      aout[p * 256 + qc0 + nt2 * 16 + l15] =
          __float2bfloat16(oacc[nt2][reg] / l[reg] + vbias);
    }
  }
}

// ---------------------------------------------------------------------------
extern "C" void kernel_launch(void* const* d_in, const int* in_sizes, int n_in,
                              void* d_out, int out_size, void* d_ws, size_t ws_size,
                              hipStream_t stream) {
  (void)in_sizes; (void)n_in; (void)out_size; (void)ws_size;
  const float* x     = (const float*)d_in[0];
  const float* ln1g  = (const float*)d_in[1];
  const float* ln1b  = (const float*)d_in[2];
  const float* q_w   = (const float*)d_in[3];
  const float* q_b   = (const float*)d_in[4];
  const float* k_w   = (const float*)d_in[5];
  const float* k_b   = (const float*)d_in[6];
  const float* v_w   = (const float*)d_in[7];
  const float* v_b   = (const float*)d_in[8];
  const float* off1w = (const float*)d_in[9];
  const float* off2w = (const float*)d_in[10];
  const float* off3w = (const float*)d_in[11];
  const float* bng   = (const float*)d_in[12];
  const float* bnb   = (const float*)d_in[13];
  const float* bnm   = (const float*)d_in[14];
  const float* bnv   = (const float*)d_in[15];
  const float* off4w = (const float*)d_in[16];
  const float* pe    = (const float*)d_in[17];
  const float* pjw   = (const float*)d_in[18];
  const float* pjb   = (const float*)d_in[19];
  const float* ln2g  = (const float*)d_in[20];
  const float* ln2b  = (const float*)d_in[21];
  const float* w1    = (const float*)d_in[22];
  const float* b1    = (const float*)d_in[23];
  const float* w2    = (const float*)d_in[24];
  const float* b2    = (const float*)d_in[25];
  (void)k_b;
  float* outp = (float*)d_out;

  char* W = (char*)d_ws;
  bf16*  xa    = (bf16*) (W + 0);          // [8192][256]; reused as aout/xm
  float* dw1   = (float*)(W + 8388608);    // [4][1024][128] f32
  float* dw2   = (float*)(W + 10485760);   // [4][256][128] f32
  bf16*  dw3b  = (bf16*) (W + 11010048);   // [4][64][128] bf16
  bf16*  qkv   = (bf16*) (W + 13238272);   // [5][8192][256]
  bf16*  qb    = qkv;
  bf16*  Kimg  = qkv + 2097152;
  bf16*  Vimg  = qkv + 3 * 2097152;
  bf16*  x2    = (bf16*) (W + 34209792);
  float* xnhwc = (float*)(W + 38404096);
  unsigned short* wqkv   = (unsigned short*)(W + 46792704);
  float*          bqkv   = (float*)         (W + 47448064);
  unsigned short* wproj  = (unsigned short*)(W + 47453184);
  unsigned short* wmlp1  = (unsigned short*)(W + 47584256);
  unsigned short* wmlp2  = (unsigned short*)(W + 48108544);
  unsigned short* woff4i = (unsigned short*)(W + 48632832);
  int*   goff  = (int*)  (W + 49157120);
  float* gwt   = (float*)(W + 50205696);
  bf16*  aout = xa;
  bf16*  xm   = xa;
  bf16*  hdn  = Kimg;

  // 1. setup: LN1 + all weight prep in one launch
  setup_kernel<<<4869, 256, 0, stream>>>(
      x, ln1g, ln1b, q_w, q_b, k_w, v_w, pjw, w1, w2, off4w,
      xa, xnhwc, wqkv, bqkv, wproj, wmlp1, wmlp2, woff4i);
  // 2. fused QKV GEMM: N=1280 -> q | Kimg | Vimg
  mgemm_kernel<4, 0, 0, 128><<<dim3(20, 64), 256, 0, stream>>>(
      xa, wqkv, bqkv, nullptr, qkv, 1280, 256, 256, 256);
  // 3. offset branch: three parallel depthwise launches (r10 structure)
  dwconv_kernel<bf16, float, 256><<<2048, 256, 0, stream>>>(
      qb, off1w, dw1, 64, 64, 32, 32, 0, nullptr, nullptr, nullptr, nullptr);
  dwconv_kernel<float, float, 128><<<512, 256, 0, stream>>>(
      dw1, off2w, dw2, 32, 32, 16, 16, 0, nullptr, nullptr, nullptr, nullptr);
  dwconv_kernel<float, bf16, 128><<<128, 256, 0, stream>>>(
      dw2, off3w, dw3b, 16, 16, 8, 8, 1, bng, bnb, bnm, bnv);
  // 4. offset head GEMM + tanh/grid + coord pack (OUTM=5)
  mgemm_kernel<5, 0, 0, 128><<<dim3(32, 2), 256, 0, stream>>>(
      dw3b, woff4i, nullptr, (const void*)gwt, goff, 2048, 128, 128, 128);
  // 5. fused attention (pipelined gather from precomputed offsets/weights)
  attn_kernel<<<1024, 256, 0, stream>>>(
      qb, (const unsigned short*)Kimg, (const unsigned short*)Vimg,
      goff, gwt, v_b, pe, aout);
  // 6. proj + residual(x_nhwc f32) -> x2 NHWC bf16
  mgemm_kernel<0, 1, 0, 64><<<dim3(4, 128), 256, 0, stream>>>(
      aout, wproj, pjb, (const void*)xnhwc, x2, 256, 256, 256, 256);
  // 7. LN2 -> xm
  ln2_kernel<<<256, 256, 0, stream>>>(x2, ln2g, ln2b, xm);
  // 8. MLP1 + GELU -> hdn
  mgemm_kernel<0, 0, 1, 128><<<dim3(16, 64), 256, 0, stream>>>(
      xm, wmlp1, b1, nullptr, hdn, 1024, 256, 256, 256);
  // 9. MLP2 + residual(x2) -> f32 NCHW d_out via LDS transpose
  mgemm_kernel<1, 2, 0, 64><<<dim3(4, 128), 256, 0, stream>>>(
      hdn, wmlp2, b2, (const void*)x2, outp, 256, 1024, 1024, 1024);
}